// Round 6
// baseline (103.648 us; speedup 1.0000x reference)
//
#include <hip/hip_runtime.h>
#include <hip/hip_bf16.h>

typedef _Float16 f16;
typedef f16 f16x8 __attribute__((ext_vector_type(8)));
typedef f16 f16x4 __attribute__((ext_vector_type(4)));
typedef float f32x4 __attribute__((ext_vector_type(4)));

#define MFMA_F16(a, b, c) __builtin_amdgcn_mfma_f32_16x16x32_f16((a), (b), (c), 0, 0, 0)

// ---------------------------------------------------------------------------
// async global->LDS 16B copy
// ---------------------------------------------------------------------------
__device__ __forceinline__ void ld_lds16(const void* g, void* l) {
  __builtin_amdgcn_global_load_lds((const __attribute__((address_space(1))) void*)g,
                                   (__attribute__((address_space(3))) void*)l, 16, 0, 0);
}

// ---------------------------------------------------------------------------
// cast fp32 -> fp16 for hidden (2M) + 4 weight matrices (1M each), float4-wide
// ---------------------------------------------------------------------------
__global__ __launch_bounds__(256) void cast_all(
    const float* __restrict__ hs, const float* __restrict__ wq,
    const float* __restrict__ wk, const float* __restrict__ wv,
    const float* __restrict__ wo, f16* __restrict__ hb,
    f16* __restrict__ wqb, f16* __restrict__ wkb,
    f16* __restrict__ wvb, f16* __restrict__ wob) {
  int idx = blockIdx.x * 256 + threadIdx.x;  // 1,572,864 float4 chunks total
  const float* src;
  f16* dst;
  int j;
  if (idx < 524288) {  // hidden: 2M floats / 4
    src = hs; dst = hb; j = idx;
  } else {
    int t = idx - 524288;
    int w = t >> 18;      // 262144 float4 per weight
    j = t & 262143;
    src = (w == 0) ? wq : (w == 1) ? wk : (w == 2) ? wv : wo;
    dst = (w == 0) ? wqb : (w == 1) ? wkb : (w == 2) ? wvb : wob;
  }
  float4 v = ((const float4*)src)[j];
  f16x4 o;
  o[0] = (f16)v.x; o[1] = (f16)v.y; o[2] = (f16)v.z; o[3] = (f16)v.w;
  ((f16x4*)dst)[j] = o;
}

// ---------------------------------------------------------------------------
// relative-position bias table: btab[h][rel + 2047], rel = kv - q
// ---------------------------------------------------------------------------
__global__ __launch_bounds__(256) void build_bias(const float* __restrict__ rb,
                                                  float* __restrict__ btab) {
  int idx = blockIdx.x * 256 + threadIdx.x;  // 65536 = 16 heads * 4096
  int h = idx >> 12;
  int t = idx & 4095;
  int rel = t - 2047;
  int bucket = (rel > 0) ? 16 : 0;
  int a = (rel < 0) ? -rel : rel;
  int lg;
  if (a < 8) {
    lg = a;
  } else {
    int cnt = (a >= 12) + (a >= 16) + (a >= 23) + (a >= 32) + (a >= 46) +
              (a >= 64) + (a >= 91);
    lg = 8 + cnt;  // max 15
  }
  bucket += lg;
  btab[idx] = rb[bucket * 16 + h];  // rel_bias[32][16]
}

// ---------------------------------------------------------------------------
// GEMM mainloop: C[64x128] tile of A[M,1024] * B[N,1024]^T (both row-major).
// 256 threads = 4 waves (1x4 over N); wave owns 64x32 out = 4x2 frags.
// BK=64; LDS XOR-swizzled (chunk ^= row&7), both-sides scheme.
// ---------------------------------------------------------------------------
__device__ __forceinline__ void gemm_mainloop(const f16* __restrict__ A,
                                              const f16* __restrict__ B,
                                              int brow, int bcol,
                                              f16* lA, f16* lB,
                                              f32x4 acc[4][2]) {
  const int tid = threadIdx.x;
  const int lane = tid & 63;
  const int wn = tid >> 6;
  const int lo = lane & 15;
  const int hi = lane >> 4;
  const int sw = lo & 7;
  const int sr = tid >> 3;                       // 0..31
  const int se = (((tid & 7) ^ (sr & 7)) << 3);  // swizzled col elem offset
  const f16* gA = A + (size_t)(brow + sr) * 1024 + se;
  const f16* gB = B + (size_t)(bcol + sr) * 1024 + se;
  f16* laD = lA + tid * 8;
  f16* lbD = lB + tid * 8;
  for (int k0 = 0; k0 < 1024; k0 += 64) {
    ld_lds16(gA + k0,             laD);
    ld_lds16(gA + k0 + 32 * 1024, laD + 2048);
    ld_lds16(gB + k0,             lbD);
    ld_lds16(gB + k0 + 32 * 1024, lbD + 2048);
    ld_lds16(gB + k0 + 64 * 1024, lbD + 4096);
    ld_lds16(gB + k0 + 96 * 1024, lbD + 6144);
    __syncthreads();
    f16x8 af[4][2], bf[2][2];
#pragma unroll
    for (int m = 0; m < 4; ++m)
#pragma unroll
      for (int ks = 0; ks < 2; ++ks)
        af[m][ks] = *(const f16x8*)(lA + (m * 16 + lo) * 64 +
                                    (((ks << 2) | hi) ^ sw) * 8);
#pragma unroll
    for (int j = 0; j < 2; ++j)
#pragma unroll
      for (int ks = 0; ks < 2; ++ks)
        bf[j][ks] = *(const f16x8*)(lB + (wn * 32 + j * 16 + lo) * 64 +
                                    (((ks << 2) | hi) ^ sw) * 8);
#pragma unroll
    for (int m = 0; m < 4; ++m)
#pragma unroll
      for (int j = 0; j < 2; ++j)
#pragma unroll
        for (int ks = 0; ks < 2; ++ks)
          acc[m][j] = MFMA_F16(af[m][ks], bf[j][ks], acc[m][j]);
    __syncthreads();
  }
}

// QKV projections fused over blockIdx.z (0=Q, 1=K, 2=V-transposed)
__global__ __launch_bounds__(256) void gemm_qkv(
    const f16* __restrict__ A, const f16* __restrict__ Wq,
    const f16* __restrict__ Wk, const f16* __restrict__ Wv,
    f16* __restrict__ Qo, f16* __restrict__ Ko, f16* __restrict__ VTo) {
  __shared__ __align__(16) f16 lA[64 * 64];
  __shared__ __align__(16) f16 lB[128 * 64];
  const int z = blockIdx.z;
  const f16* B = (z == 0) ? Wq : (z == 1) ? Wk : Wv;
  const int brow = blockIdx.x * 64, bcol = blockIdx.y * 128;
  f32x4 acc[4][2];
#pragma unroll
  for (int m = 0; m < 4; ++m)
#pragma unroll
    for (int j = 0; j < 2; ++j) acc[m][j] = f32x4{0.f, 0.f, 0.f, 0.f};
  gemm_mainloop(A, B, brow, bcol, lA, lB, acc);
  const int lane = threadIdx.x & 63, wn = threadIdx.x >> 6;
  const int lo = lane & 15, hi = lane >> 4;
  if (z < 2) {
    f16* C = z ? Ko : Qo;
#pragma unroll
    for (int m = 0; m < 4; ++m)
#pragma unroll
      for (int j = 0; j < 2; ++j) {
        int col = bcol + wn * 32 + j * 16 + lo;
        int row0 = brow + m * 16 + hi * 4;
#pragma unroll
        for (int r = 0; r < 4; ++r)
          C[(size_t)(row0 + r) * 1024 + col] = (f16)acc[m][j][r];
      }
  } else {
    // V transposed: VT[n][s], n = h*64+dv
#pragma unroll
    for (int m = 0; m < 4; ++m)
#pragma unroll
      for (int j = 0; j < 2; ++j) {
        int col = bcol + wn * 32 + j * 16 + lo;   // n
        int row0 = brow + m * 16 + hi * 4;        // s
        f16x4 v4;
#pragma unroll
        for (int r = 0; r < 4; ++r) v4[r] = (f16)acc[m][j][r];
        *(f16x4*)(VTo + (size_t)col * 2048 + row0) = v4;
      }
  }
}

// output projection: AO[2048,1024] * Wo[1024,1024]^T -> fp32 d_out
__global__ __launch_bounds__(256) void gemm_out(const f16* __restrict__ A,
                                                const f16* __restrict__ W,
                                                float* __restrict__ C) {
  __shared__ __align__(16) f16 lA[64 * 64];
  __shared__ __align__(16) f16 lB[128 * 64];
  const int brow = blockIdx.x * 64, bcol = blockIdx.y * 128;
  f32x4 acc[4][2];
#pragma unroll
  for (int m = 0; m < 4; ++m)
#pragma unroll
    for (int j = 0; j < 2; ++j) acc[m][j] = f32x4{0.f, 0.f, 0.f, 0.f};
  gemm_mainloop(A, W, brow, bcol, lA, lB, acc);
  const int lane = threadIdx.x & 63, wn = threadIdx.x >> 6;
  const int lo = lane & 15, hi = lane >> 4;
#pragma unroll
  for (int m = 0; m < 4; ++m)
#pragma unroll
    for (int j = 0; j < 2; ++j) {
      int col = bcol + wn * 32 + j * 16 + lo;
      int row0 = brow + m * 16 + hi * 4;
#pragma unroll
      for (int r = 0; r < 4; ++r)
        C[(size_t)(row0 + r) * 1024 + col] = acc[m][j][r];
    }
}

// ---------------------------------------------------------------------------
// Flash attention v5: r4 per-wave structure unchanged, but KV range split
// across blockIdx.z (2 halves of 1024 kv each) -> 1024 blocks = 4 blocks/CU
// = 4 waves/SIMD (2x latency hiding). Each half writes NORMALIZED partial
// O (f16) + (m,l); merge_halves combines exactly.
// ---------------------------------------------------------------------------
__global__ __launch_bounds__(256, 2) void attn_kernel(
    const f16* __restrict__ Q, const f16* __restrict__ K,
    const f16* __restrict__ VT, const float* __restrict__ btab,
    f16* __restrict__ Oh, float2* __restrict__ Ml) {
  __shared__ __align__(16) f16 lK[2][4096];
  __shared__ __align__(16) f16 lV[2][4096];

  const int h = blockIdx.y;
  const int q0 = blockIdx.x * 64;
  const int z = blockIdx.z;
  const int kvBase = z * 1024;
  const int tid = threadIdx.x;
  const int wave = tid >> 6, lane = tid & 63;
  const int lo = lane & 15, hi = lane >> 4;
  const int sw = lo & 7;
  const int myq = q0 + wave * 16 + lo;

  const f16* Kh = K + h * 64;
  const f16* VTh = VT + (size_t)h * 64 * 2048;
  const float* bt = btab + h * 4096 + 2047 - myq;

  f16x8 qf[2];
#pragma unroll
  for (int kk = 0; kk < 2; ++kk)
    qf[kk] = *(const f16x8*)(Q + (size_t)myq * 1024 + h * 64 + kk * 32 + hi * 8);

  const int sc0 = wave * 64 + lane;
  const int sc1 = 256 + sc0;
  const int r0 = sc0 >> 3, e0 = (sc0 & 7) ^ (r0 & 7);
  const int r1 = sc1 >> 3, e1 = (sc1 & 7) ^ (r1 & 7);

#define STAGE(bufi, kv)                                                        \
  do {                                                                         \
    ld_lds16(Kh + (size_t)((kv) + r0) * 1024 + e0 * 8, &lK[bufi][sc0 * 8]);    \
    ld_lds16(Kh + (size_t)((kv) + r1) * 1024 + e1 * 8, &lK[bufi][sc1 * 8]);    \
    ld_lds16(VTh + (size_t)r0 * 2048 + (kv) + e0 * 8, &lV[bufi][sc0 * 8]);     \
    ld_lds16(VTh + (size_t)r1 * 2048 + (kv) + e1 * 8, &lV[bufi][sc1 * 8]);     \
  } while (0)

  float m_run = -1e30f, l_run = 0.f;
  f32x4 oacc[4];
#pragma unroll
  for (int d = 0; d < 4; ++d) oacc[d] = f32x4{0.f, 0.f, 0.f, 0.f};

  f16x8 vfA[4][2], vfB[4][2];
  f32x4 saccA[4], saccB[4];
  float biasA[16], biasB[16];

#define TILE_FRONT(t_, CUR)                                                    \
  {                                                                            \
    const int b_ = (t_) & 1;                                                   \
    const int kv0_ = kvBase + (t_) * 64;                                       \
    const f16* lKb_ = lK[b_];                                                  \
    const f16* lVb_ = lV[b_];                                                  \
    f16x8 kf_[4][2];                                                           \
    _Pragma("unroll") for (int m_ = 0; m_ < 4; ++m_)                           \
      _Pragma("unroll") for (int kk_ = 0; kk_ < 2; ++kk_)                      \
        kf_[m_][kk_] = *(const f16x8*)&lKb_[(m_ * 16 + lo) * 64 +              \
                                            (((kk_ << 2) | hi) ^ sw) * 8];     \
    _Pragma("unroll") for (int d_ = 0; d_ < 4; ++d_)                           \
      _Pragma("unroll") for (int kk_ = 0; kk_ < 2; ++kk_) {                    \
        const int row_ = d_ * 16 + lo;                                         \
        const int cc_ = kk_ * 4 + (hi >> 1);                                   \
        const int ia_ = (hi & 1) * 4;                                          \
        f16x4 vlo_ = *(const f16x4*)&lVb_[row_ * 64 + (cc_ ^ sw) * 8 + ia_];   \
        f16x4 vhi_ =                                                           \
            *(const f16x4*)&lVb_[row_ * 64 + ((cc_ + 2) ^ sw) * 8 + ia_];      \
        _Pragma("unroll") for (int r_ = 0; r_ < 4; ++r_) {                     \
          vf##CUR[d_][kk_][r_] = vlo_[r_];                                     \
          vf##CUR[d_][kk_][r_ + 4] = vhi_[r_];                                 \
        }                                                                      \
      }                                                                        \
    if ((t_) < 15) STAGE(1 - b_, kv0_ + 64);                                   \
    _Pragma("unroll") for (int i_ = 0; i_ < 16; ++i_)                          \
      bias##CUR[i_] = bt[kv0_ + (i_ >> 2) * 16 + hi * 4 + (i_ & 3)];           \
    __builtin_amdgcn_s_setprio(1);                                             \
    _Pragma("unroll") for (int m_ = 0; m_ < 4; ++m_) {                         \
      sacc##CUR[m_] = f32x4{0.f, 0.f, 0.f, 0.f};                               \
      _Pragma("unroll") for (int kk_ = 0; kk_ < 2; ++kk_)                      \
        sacc##CUR[m_] = MFMA_F16(kf_[m_][kk_], qf[kk_], sacc##CUR[m_]);        \
    }                                                                          \
    __builtin_amdgcn_s_setprio(0);                                             \
  }

#define SOFTMAX_PV(PRV)                                                        \
  {                                                                            \
    float p_[16];                                                              \
    float mx_ = -1e30f;                                                        \
    _Pragma("unroll") for (int i_ = 0; i_ < 16; ++i_) {                        \
      float s_ = sacc##PRV[i_ >> 2][i_ & 3] + bias##PRV[i_];                   \
      p_[i_] = s_;                                                             \
      mx_ = fmaxf(mx_, s_);                                                    \
    }                                                                          \
    mx_ = fmaxf(mx_, __shfl_xor(mx_, 16, 64));                                 \
    mx_ = fmaxf(mx_, __shfl_xor(mx_, 32, 64));                                 \
    if (!__all(mx_ <= m_run + 8.0f)) {                                         \
      float mn_ = fmaxf(m_run, mx_);                                           \
      float sc_ = __expf(m_run - mn_);                                         \
      l_run *= sc_;                                                            \
      _Pragma("unroll") for (int d_ = 0; d_ < 4; ++d_) oacc[d_] *= sc_;        \
      m_run = mn_;                                                             \
    }                                                                          \
    float ps_ = 0.f;                                                           \
    _Pragma("unroll") for (int i_ = 0; i_ < 16; ++i_) {                        \
      p_[i_] = __expf(p_[i_] - m_run);                                         \
      ps_ += p_[i_];                                                           \
    }                                                                          \
    ps_ += __shfl_xor(ps_, 16, 64);                                            \
    ps_ += __shfl_xor(ps_, 32, 64);                                            \
    l_run += ps_;                                                              \
    f16x8 pf_[2];                                                              \
    _Pragma("unroll") for (int kk_ = 0; kk_ < 2; ++kk_)                        \
      _Pragma("unroll") for (int j_ = 0; j_ < 8; ++j_)                         \
        pf_[kk_][j_] = (f16)p_[(kk_ * 2 + (j_ >> 2)) * 4 + (j_ & 3)];          \
    __builtin_amdgcn_s_setprio(1);                                             \
    _Pragma("unroll") for (int d_ = 0; d_ < 4; ++d_)                           \
      _Pragma("unroll") for (int kk_ = 0; kk_ < 2; ++kk_)                      \
        oacc[d_] = MFMA_F16(vf##PRV[d_][kk_], pf_[kk_], oacc[d_]);             \
    __builtin_amdgcn_s_setprio(0);                                             \
  }

  STAGE(0, kvBase);
  __syncthreads();

  TILE_FRONT(0, A);
  __syncthreads();

  for (int k2 = 0; k2 < 7; ++k2) {
    const int t1 = 2 * k2 + 1;  // 1,3,...,13
    TILE_FRONT(t1, B);
    SOFTMAX_PV(A);
    __syncthreads();
    TILE_FRONT(t1 + 1, A);  // 2,4,...,14
    SOFTMAX_PV(B);
    __syncthreads();
  }
  TILE_FRONT(15, B);
  SOFTMAX_PV(A);
  SOFTMAX_PV(B);

#undef TILE_FRONT
#undef SOFTMAX_PV
#undef STAGE

  // ---- epilogue: normalized partial O -> Oh[z], (m,l) -> Ml[z] ----
  float inv = 1.f / l_run;
  f16* OhZ = Oh + (size_t)z * 2048 * 1024;
#pragma unroll
  for (int d = 0; d < 4; ++d) {
    f16x4 ov;
#pragma unroll
    for (int r = 0; r < 4; ++r) ov[r] = (f16)(oacc[d][r] * inv);
    *(f16x4*)(OhZ + (size_t)myq * 1024 + h * 64 + d * 16 + hi * 4) = ov;
  }
  if (hi == 0) Ml[(z * 16 + h) * 2048 + myq] = float2{m_run, l_run};
}

// ---------------------------------------------------------------------------
// exact merge of the two KV-half partials: AO = w0*Oh0 + w1*Oh1
// ---------------------------------------------------------------------------
__global__ __launch_bounds__(256) void merge_halves(
    const f16* __restrict__ Oh, const float2* __restrict__ Ml,
    f16* __restrict__ AO) {
  int idx = blockIdx.x * 256 + threadIdx.x;  // 262144 f16x8 chunks
  int q = idx >> 7;                          // 128 chunks per q-row
  int h = (idx & 127) >> 3;                  // 8 chunks per head
  float2 ml0 = Ml[h * 2048 + q];
  float2 ml1 = Ml[(16 + h) * 2048 + q];
  float M = fmaxf(ml0.x, ml1.x);
  float w0 = ml0.y * __expf(ml0.x - M);
  float w1 = ml1.y * __expf(ml1.x - M);
  float inv = 1.f / (w0 + w1);
  w0 *= inv;
  w1 *= inv;
  f16x8 a = ((const f16x8*)Oh)[idx];
  f16x8 b = ((const f16x8*)(Oh + (size_t)2048 * 1024))[idx];
  f16x8 o;
#pragma unroll
  for (int r = 0; r < 8; ++r)
    o[r] = (f16)(w0 * (float)a[r] + w1 * (float)b[r]);
  ((f16x8*)AO)[idx] = o;
}

// ---------------------------------------------------------------------------
extern "C" void kernel_launch(void* const* d_in, const int* in_sizes, int n_in,
                              void* d_out, int out_size, void* d_ws, size_t ws_size,
                              hipStream_t stream) {
  const float* hs = (const float*)d_in[0];
  const float* wq = (const float*)d_in[1];
  const float* wk = (const float*)d_in[2];
  const float* wv = (const float*)d_in[3];
  const float* wo = (const float*)d_in[4];
  const float* rb = (const float*)d_in[5];

  char* w = (char*)d_ws;
  f16* hb  = (f16*)w; w += (size_t)2048 * 1024 * 2;
  f16* wqb = (f16*)w; w += (size_t)1024 * 1024 * 2;
  f16* wkb = (f16*)w; w += (size_t)1024 * 1024 * 2;
  f16* wvb = (f16*)w; w += (size_t)1024 * 1024 * 2;
  f16* wob = (f16*)w; w += (size_t)1024 * 1024 * 2;
  f16* Qb  = (f16*)w; w += (size_t)2048 * 1024 * 2;
  f16* Kb  = (f16*)w; w += (size_t)2048 * 1024 * 2;
  f16* VTb = (f16*)w; w += (size_t)2048 * 1024 * 2;
  f16* AOb = (f16*)w; w += (size_t)2048 * 1024 * 2;
  float* btab = (float*)w; w += (size_t)16 * 4096 * 4;

  // partial buffers reuse hb/wqb/wkb (8 MB, dead after gemm_qkv) and wvb:
  f16* Oh = hb;                 // [2][2048][1024] f16 = 8 MB (hb+wqb+wkb)
  float2* Ml = (float2*)wvb;    // [2][16][2048] float2 = 512 KB

  cast_all<<<6144, 256, 0, stream>>>(hs, wq, wk, wv, wo, hb, wqb, wkb, wvb, wob);
  build_bias<<<256, 256, 0, stream>>>(rb, btab);
  gemm_qkv<<<dim3(32, 8, 3), 256, 0, stream>>>(hb, wqb, wkb, wvb, Qb, Kb, VTb);
  attn_kernel<<<dim3(32, 16, 2), 256, 0, stream>>>(Qb, Kb, VTb, btab, Oh, Ml);
  merge_halves<<<1024, 256, 0, stream>>>(Oh, Ml, AOb);
  gemm_out<<<dim3(32, 8), 256, 0, stream>>>(AOb, wob, (float*)d_out);
}

// Round 7
// 101.703 us; speedup vs baseline: 1.0191x; 1.0191x over previous
//
#include <hip/hip_runtime.h>
#include <hip/hip_bf16.h>

typedef _Float16 f16;
typedef f16 f16x8 __attribute__((ext_vector_type(8)));
typedef f16 f16x4 __attribute__((ext_vector_type(4)));
typedef float f32x4 __attribute__((ext_vector_type(4)));

#define MFMA_F16(a, b, c) __builtin_amdgcn_mfma_f32_16x16x32_f16((a), (b), (c), 0, 0, 0)

// ---------------------------------------------------------------------------
// async global->LDS 16B copy
// ---------------------------------------------------------------------------
__device__ __forceinline__ void ld_lds16(const void* g, void* l) {
  __builtin_amdgcn_global_load_lds((const __attribute__((address_space(1))) void*)g,
                                   (__attribute__((address_space(3))) void*)l, 16, 0, 0);
}

// ---------------------------------------------------------------------------
// cast fp32 -> fp16 for hidden (2M) + 4 weight matrices (1M each), float4-wide
// ---------------------------------------------------------------------------
__global__ __launch_bounds__(256) void cast_all(
    const float* __restrict__ hs, const float* __restrict__ wq,
    const float* __restrict__ wk, const float* __restrict__ wv,
    const float* __restrict__ wo, f16* __restrict__ hb,
    f16* __restrict__ wqb, f16* __restrict__ wkb,
    f16* __restrict__ wvb, f16* __restrict__ wob) {
  int idx = blockIdx.x * 256 + threadIdx.x;  // 1,572,864 float4 chunks total
  const float* src;
  f16* dst;
  int j;
  if (idx < 524288) {  // hidden: 2M floats / 4
    src = hs; dst = hb; j = idx;
  } else {
    int t = idx - 524288;
    int w = t >> 18;      // 262144 float4 per weight
    j = t & 262143;
    src = (w == 0) ? wq : (w == 1) ? wk : (w == 2) ? wv : wo;
    dst = (w == 0) ? wqb : (w == 1) ? wkb : (w == 2) ? wvb : wob;
  }
  float4 v = ((const float4*)src)[j];
  f16x4 o;
  o[0] = (f16)v.x; o[1] = (f16)v.y; o[2] = (f16)v.z; o[3] = (f16)v.w;
  ((f16x4*)dst)[j] = o;
}

// ---------------------------------------------------------------------------
// relative-position bias table: btab[h][rel + 2047], rel = kv - q
// ---------------------------------------------------------------------------
__global__ __launch_bounds__(256) void build_bias(const float* __restrict__ rb,
                                                  float* __restrict__ btab) {
  int idx = blockIdx.x * 256 + threadIdx.x;  // 65536 = 16 heads * 4096
  int h = idx >> 12;
  int t = idx & 4095;
  int rel = t - 2047;
  int bucket = (rel > 0) ? 16 : 0;
  int a = (rel < 0) ? -rel : rel;
  int lg;
  if (a < 8) {
    lg = a;
  } else {
    int cnt = (a >= 12) + (a >= 16) + (a >= 23) + (a >= 32) + (a >= 46) +
              (a >= 64) + (a >= 91);
    lg = 8 + cnt;  // max 15
  }
  bucket += lg;
  btab[idx] = rb[bucket * 16 + h];  // rel_bias[32][16]
}

// ---------------------------------------------------------------------------
// GEMM mainloop: C[64x128] tile of A[M,1024] * B[N,1024]^T (both row-major).
// 256 threads = 4 waves (1x4 over N); wave owns 64x32 out = 4x2 frags.
// BK=64; LDS XOR-swizzled (chunk ^= row&7), both-sides scheme.
// ---------------------------------------------------------------------------
__device__ __forceinline__ void gemm_mainloop(const f16* __restrict__ A,
                                              const f16* __restrict__ B,
                                              int brow, int bcol,
                                              f16* lA, f16* lB,
                                              f32x4 acc[4][2]) {
  const int tid = threadIdx.x;
  const int lane = tid & 63;
  const int wn = tid >> 6;
  const int lo = lane & 15;
  const int hi = lane >> 4;
  const int sw = lo & 7;
  const int sr = tid >> 3;                       // 0..31
  const int se = (((tid & 7) ^ (sr & 7)) << 3);  // swizzled col elem offset
  const f16* gA = A + (size_t)(brow + sr) * 1024 + se;
  const f16* gB = B + (size_t)(bcol + sr) * 1024 + se;
  f16* laD = lA + tid * 8;
  f16* lbD = lB + tid * 8;
  for (int k0 = 0; k0 < 1024; k0 += 64) {
    ld_lds16(gA + k0,             laD);
    ld_lds16(gA + k0 + 32 * 1024, laD + 2048);
    ld_lds16(gB + k0,             lbD);
    ld_lds16(gB + k0 + 32 * 1024, lbD + 2048);
    ld_lds16(gB + k0 + 64 * 1024, lbD + 4096);
    ld_lds16(gB + k0 + 96 * 1024, lbD + 6144);
    __syncthreads();
    f16x8 af[4][2], bf[2][2];
#pragma unroll
    for (int m = 0; m < 4; ++m)
#pragma unroll
      for (int ks = 0; ks < 2; ++ks)
        af[m][ks] = *(const f16x8*)(lA + (m * 16 + lo) * 64 +
                                    (((ks << 2) | hi) ^ sw) * 8);
#pragma unroll
    for (int j = 0; j < 2; ++j)
#pragma unroll
      for (int ks = 0; ks < 2; ++ks)
        bf[j][ks] = *(const f16x8*)(lB + (wn * 32 + j * 16 + lo) * 64 +
                                    (((ks << 2) | hi) ^ sw) * 8);
#pragma unroll
    for (int m = 0; m < 4; ++m)
#pragma unroll
      for (int j = 0; j < 2; ++j)
#pragma unroll
        for (int ks = 0; ks < 2; ++ks)
          acc[m][j] = MFMA_F16(af[m][ks], bf[j][ks], acc[m][j]);
    __syncthreads();
  }
}

// QKV projections fused over blockIdx.z (0=Q, 1=K, 2=V-transposed)
__global__ __launch_bounds__(256) void gemm_qkv(
    const f16* __restrict__ A, const f16* __restrict__ Wq,
    const f16* __restrict__ Wk, const f16* __restrict__ Wv,
    f16* __restrict__ Qo, f16* __restrict__ Ko, f16* __restrict__ VTo) {
  __shared__ __align__(16) f16 lA[64 * 64];
  __shared__ __align__(16) f16 lB[128 * 64];
  const int z = blockIdx.z;
  const f16* B = (z == 0) ? Wq : (z == 1) ? Wk : Wv;
  const int brow = blockIdx.x * 64, bcol = blockIdx.y * 128;
  f32x4 acc[4][2];
#pragma unroll
  for (int m = 0; m < 4; ++m)
#pragma unroll
    for (int j = 0; j < 2; ++j) acc[m][j] = f32x4{0.f, 0.f, 0.f, 0.f};
  gemm_mainloop(A, B, brow, bcol, lA, lB, acc);
  const int lane = threadIdx.x & 63, wn = threadIdx.x >> 6;
  const int lo = lane & 15, hi = lane >> 4;
  if (z < 2) {
    f16* C = z ? Ko : Qo;
#pragma unroll
    for (int m = 0; m < 4; ++m)
#pragma unroll
      for (int j = 0; j < 2; ++j) {
        int col = bcol + wn * 32 + j * 16 + lo;
        int row0 = brow + m * 16 + hi * 4;
#pragma unroll
        for (int r = 0; r < 4; ++r)
          C[(size_t)(row0 + r) * 1024 + col] = (f16)acc[m][j][r];
      }
  } else {
    // V transposed: VT[n][s], n = h*64+dv
#pragma unroll
    for (int m = 0; m < 4; ++m)
#pragma unroll
      for (int j = 0; j < 2; ++j) {
        int col = bcol + wn * 32 + j * 16 + lo;   // n
        int row0 = brow + m * 16 + hi * 4;        // s
        f16x4 v4;
#pragma unroll
        for (int r = 0; r < 4; ++r) v4[r] = (f16)acc[m][j][r];
        *(f16x4*)(VTo + (size_t)col * 2048 + row0) = v4;
      }
  }
}

// output projection: AO[2048,1024] * Wo[1024,1024]^T -> fp32 d_out
__global__ __launch_bounds__(256) void gemm_out(const f16* __restrict__ A,
                                                const f16* __restrict__ W,
                                                float* __restrict__ C) {
  __shared__ __align__(16) f16 lA[64 * 64];
  __shared__ __align__(16) f16 lB[128 * 64];
  const int brow = blockIdx.x * 64, bcol = blockIdx.y * 128;
  f32x4 acc[4][2];
#pragma unroll
  for (int m = 0; m < 4; ++m)
#pragma unroll
    for (int j = 0; j < 2; ++j) acc[m][j] = f32x4{0.f, 0.f, 0.f, 0.f};
  gemm_mainloop(A, W, brow, bcol, lA, lB, acc);
  const int lane = threadIdx.x & 63, wn = threadIdx.x >> 6;
  const int lo = lane & 15, hi = lane >> 4;
#pragma unroll
  for (int m = 0; m < 4; ++m)
#pragma unroll
    for (int j = 0; j < 2; ++j) {
      int col = bcol + wn * 32 + j * 16 + lo;
      int row0 = brow + m * 16 + hi * 4;
#pragma unroll
      for (int r = 0; r < 4; ++r)
        C[(size_t)(row0 + r) * 1024 + col] = acc[m][j][r];
    }
}

// ---------------------------------------------------------------------------
// Flash attention v6: T3/T4 counted-vmcnt pipeline.
// 3-buffer LDS K/V staging, depth-2 prefetch: slot t stages tile t+2; end of
// slot waits lgkmcnt(0) + vmcnt(4) + raw s_barrier -> tile t+1's 4 loads are
// retired, tile t+2's 4 stay in flight ACROSS the barrier (never drain to 0
// until the tail). Bias is staged once per block into LDS so the only in-loop
// VMEM ops are the 4 global_load_lds per slot (exact vmcnt counting).
// Compute stays 2-deep (QKT(t) || softmax+PV(t-1)), setprio on MFMA clusters.
// ---------------------------------------------------------------------------
__global__ __launch_bounds__(256, 2) void attn_kernel(
    const f16* __restrict__ Q, const f16* __restrict__ K,
    const f16* __restrict__ VT, const float* __restrict__ btab,
    f16* __restrict__ AO) {
  __shared__ __align__(16) f16 lK[3][4096];
  __shared__ __align__(16) f16 lV[3][4096];
  __shared__ __align__(16) float biasL[2112];

  const int h = blockIdx.y;
  const int q0 = blockIdx.x * 64;
  const int tid = threadIdx.x;
  const int wave = tid >> 6, lane = tid & 63;
  const int lo = lane & 15, hi = lane >> 4;
  const int sw = lo & 7;
  const int myq = q0 + wave * 16 + lo;
  const int bofs = 63 - (wave * 16 + lo);  // biasL idx = kv + bofs (per lane)

  const f16* Kh = K + h * 64;
  const f16* VTh = VT + (size_t)h * 64 * 2048;

  // ---- prologue: Q frags, bias table -> LDS, stage tiles 0,1 ----
  f16x8 qf[2];
#pragma unroll
  for (int kk = 0; kk < 2; ++kk)
    qf[kk] = *(const f16x8*)(Q + (size_t)myq * 1024 + h * 64 + kk * 32 + hi * 8);
  __builtin_amdgcn_sched_barrier(0);  // pin: qf loads issue before stages

  const int sc0 = wave * 64 + lane;
  const int sc1 = 256 + sc0;
  const int r0 = sc0 >> 3, e0 = (sc0 & 7) ^ (r0 & 7);
  const int r1 = sc1 >> 3, e1 = (sc1 & 7) ^ (r1 & 7);

#define STAGE(bufi, kv)                                                        \
  do {                                                                         \
    ld_lds16(Kh + (size_t)((kv) + r0) * 1024 + e0 * 8, &lK[bufi][sc0 * 8]);    \
    ld_lds16(Kh + (size_t)((kv) + r1) * 1024 + e1 * 8, &lK[bufi][sc1 * 8]);    \
    ld_lds16(VTh + (size_t)r0 * 2048 + (kv) + e0 * 8, &lV[bufi][sc0 * 8]);     \
    ld_lds16(VTh + (size_t)r1 * 2048 + (kv) + e1 * 8, &lV[bufi][sc1 * 8]);     \
  } while (0)

  {
    const float* bsrc = btab + h * 4096 + 1984 - q0;  // 2112 floats, 16B-aligned
    for (int c = tid; c < 528; c += 256)
      ld_lds16(bsrc + c * 4, biasL + c * 4);
  }
  STAGE(0, 0);
  STAGE(1, 64);
  asm volatile("s_waitcnt vmcnt(4)" ::: "memory");  // qf+bias+tile0 done
  __builtin_amdgcn_sched_barrier(0);
  __builtin_amdgcn_s_barrier();

  float m_run = -1e30f, l_run = 0.f;
  f32x4 oacc[4];
#pragma unroll
  for (int d = 0; d < 4; ++d) oacc[d] = f32x4{0.f, 0.f, 0.f, 0.f};

  f16x8 vfA[4][2], vfB[4][2];
  f32x4 saccA[4], saccB[4];
  float biasA[16], biasB[16];

// ds-reads (K frags, V->regs, bias->regs) + QK^T for tile t_ from buf b_
#define TILE_FRONT(t_, b_, CUR)                                                \
  {                                                                            \
    const int kv0_ = (t_) * 64;                                                \
    const f16* lKb_ = lK[b_];                                                  \
    const f16* lVb_ = lV[b_];                                                  \
    const float* bl_ = biasL + kv0_ + bofs;                                    \
    f16x8 kf_[4][2];                                                           \
    _Pragma("unroll") for (int m_ = 0; m_ < 4; ++m_)                           \
      _Pragma("unroll") for (int kk_ = 0; kk_ < 2; ++kk_)                      \
        kf_[m_][kk_] = *(const f16x8*)&lKb_[(m_ * 16 + lo) * 64 +              \
                                            (((kk_ << 2) | hi) ^ sw) * 8];     \
    _Pragma("unroll") for (int d_ = 0; d_ < 4; ++d_)                           \
      _Pragma("unroll") for (int kk_ = 0; kk_ < 2; ++kk_) {                    \
        const int row_ = d_ * 16 + lo;                                         \
        const int cc_ = kk_ * 4 + (hi >> 1);                                   \
        const int ia_ = (hi & 1) * 4;                                          \
        f16x4 vlo_ = *(const f16x4*)&lVb_[row_ * 64 + (cc_ ^ sw) * 8 + ia_];   \
        f16x4 vhi_ =                                                           \
            *(const f16x4*)&lVb_[row_ * 64 + ((cc_ + 2) ^ sw) * 8 + ia_];      \
        _Pragma("unroll") for (int r_ = 0; r_ < 4; ++r_) {                     \
          vf##CUR[d_][kk_][r_] = vlo_[r_];                                     \
          vf##CUR[d_][kk_][r_ + 4] = vhi_[r_];                                 \
        }                                                                      \
      }                                                                        \
    _Pragma("unroll") for (int i_ = 0; i_ < 16; ++i_)                          \
      bias##CUR[i_] = bl_[(i_ >> 2) * 16 + hi * 4 + (i_ & 3)];                 \
    __builtin_amdgcn_s_setprio(1);                                             \
    _Pragma("unroll") for (int m_ = 0; m_ < 4; ++m_) {                         \
      sacc##CUR[m_] = f32x4{0.f, 0.f, 0.f, 0.f};                               \
      _Pragma("unroll") for (int kk_ = 0; kk_ < 2; ++kk_)                      \
        sacc##CUR[m_] = MFMA_F16(kf_[m_][kk_], qf[kk_], sacc##CUR[m_]);        \
    }                                                                          \
    __builtin_amdgcn_s_setprio(0);                                             \
  }

#define SOFTMAX_PV(PRV)                                                        \
  {                                                                            \
    float p_[16];                                                              \
    float mx_ = -1e30f;                                                        \
    _Pragma("unroll") for (int i_ = 0; i_ < 16; ++i_) {                        \
      float s_ = sacc##PRV[i_ >> 2][i_ & 3] + bias##PRV[i_];                   \
      p_[i_] = s_;                                                             \
      mx_ = fmaxf(mx_, s_);                                                    \
    }                                                                          \
    mx_ = fmaxf(mx_, __shfl_xor(mx_, 16, 64));                                 \
    mx_ = fmaxf(mx_, __shfl_xor(mx_, 32, 64));                                 \
    if (!__all(mx_ <= m_run + 8.0f)) {                                         \
      float mn_ = fmaxf(m_run, mx_);                                           \
      float sc_ = __expf(m_run - mn_);                                         \
      l_run *= sc_;                                                            \
      _Pragma("unroll") for (int d_ = 0; d_ < 4; ++d_) oacc[d_] *= sc_;        \
      m_run = mn_;                                                             \
    }                                                                          \
    float ps_ = 0.f;                                                           \
    _Pragma("unroll") for (int i_ = 0; i_ < 16; ++i_) {                        \
      p_[i_] = __expf(p_[i_] - m_run);                                         \
      ps_ += p_[i_];                                                           \
    }                                                                          \
    ps_ += __shfl_xor(ps_, 16, 64);                                            \
    ps_ += __shfl_xor(ps_, 32, 64);                                            \
    l_run += ps_;                                                              \
    f16x8 pf_[2];                                                              \
    _Pragma("unroll") for (int kk_ = 0; kk_ < 2; ++kk_)                        \
      _Pragma("unroll") for (int j_ = 0; j_ < 8; ++j_)                         \
        pf_[kk_][j_] = (f16)p_[(kk_ * 2 + (j_ >> 2)) * 4 + (j_ & 3)];          \
    __builtin_amdgcn_s_setprio(1);                                             \
    _Pragma("unroll") for (int d_ = 0; d_ < 4; ++d_)                           \
      _Pragma("unroll") for (int kk_ = 0; kk_ < 2; ++kk_)                      \
        oacc[d_] = MFMA_F16(vf##PRV[d_][kk_], pf_[kk_], oacc[d_]);             \
    __builtin_amdgcn_s_setprio(0);                                             \
  }

// end-of-slot: ds reads in regs, older stage retired (counted), barrier
#define ENDSLOT4                                                               \
  asm volatile("s_waitcnt lgkmcnt(0)\n\ts_waitcnt vmcnt(4)" ::: "memory");     \
  __builtin_amdgcn_sched_barrier(0);                                           \
  __builtin_amdgcn_s_barrier();
#define ENDSLOT0                                                               \
  asm volatile("s_waitcnt lgkmcnt(0)\n\ts_waitcnt vmcnt(0)" ::: "memory");     \
  __builtin_amdgcn_sched_barrier(0);                                           \
  __builtin_amdgcn_s_barrier();

  // slot 0
  STAGE(2, 128);
  TILE_FRONT(0, 0, A);
  ENDSLOT4;

  // slots 1..24 (4 groups of 6: buffer pattern literal, period lcm(2,3)=6)
  for (int g = 0; g < 4; ++g) {
    const int t = g * 6;
    STAGE(0, (t + 3) * 64); TILE_FRONT(t + 1, 1, B); SOFTMAX_PV(A); ENDSLOT4;
    STAGE(1, (t + 4) * 64); TILE_FRONT(t + 2, 2, A); SOFTMAX_PV(B); ENDSLOT4;
    STAGE(2, (t + 5) * 64); TILE_FRONT(t + 3, 0, B); SOFTMAX_PV(A); ENDSLOT4;
    STAGE(0, (t + 6) * 64); TILE_FRONT(t + 4, 1, A); SOFTMAX_PV(B); ENDSLOT4;
    STAGE(1, (t + 7) * 64); TILE_FRONT(t + 5, 2, B); SOFTMAX_PV(A); ENDSLOT4;
    STAGE(2, (t + 8) * 64); TILE_FRONT(t + 6, 0, A); SOFTMAX_PV(B); ENDSLOT4;
  }
  // slots 25..29
  STAGE(0, 27 * 64); TILE_FRONT(25, 1, B); SOFTMAX_PV(A); ENDSLOT4;
  STAGE(1, 28 * 64); TILE_FRONT(26, 2, A); SOFTMAX_PV(B); ENDSLOT4;
  STAGE(2, 29 * 64); TILE_FRONT(27, 0, B); SOFTMAX_PV(A); ENDSLOT4;
  STAGE(0, 30 * 64); TILE_FRONT(28, 1, A); SOFTMAX_PV(B); ENDSLOT4;
  STAGE(1, 31 * 64); TILE_FRONT(29, 2, B); SOFTMAX_PV(A); ENDSLOT4;
  // slot 30: no stage left; drain tile 31's loads fully
  TILE_FRONT(30, 0, A); SOFTMAX_PV(B); ENDSLOT0;
  // slot 31: last tile; no barrier needed after
  TILE_FRONT(31, 1, B); SOFTMAX_PV(A);
  SOFTMAX_PV(B);

#undef TILE_FRONT
#undef SOFTMAX_PV
#undef STAGE
#undef ENDSLOT4
#undef ENDSLOT0

  // ---- epilogue: O[dv][q] / l -> AO[s][h*64+dv] ----
  float inv = 1.f / l_run;
#pragma unroll
  for (int d = 0; d < 4; ++d) {
    f16x4 ov;
#pragma unroll
    for (int r = 0; r < 4; ++r) ov[r] = (f16)(oacc[d][r] * inv);
    *(f16x4*)(AO + (size_t)myq * 1024 + h * 64 + d * 16 + hi * 4) = ov;
  }
}

// ---------------------------------------------------------------------------
extern "C" void kernel_launch(void* const* d_in, const int* in_sizes, int n_in,
                              void* d_out, int out_size, void* d_ws, size_t ws_size,
                              hipStream_t stream) {
  const float* hs = (const float*)d_in[0];
  const float* wq = (const float*)d_in[1];
  const float* wk = (const float*)d_in[2];
  const float* wv = (const float*)d_in[3];
  const float* wo = (const float*)d_in[4];
  const float* rb = (const float*)d_in[5];

  char* w = (char*)d_ws;
  f16* hb  = (f16*)w; w += (size_t)2048 * 1024 * 2;
  f16* wqb = (f16*)w; w += (size_t)1024 * 1024 * 2;
  f16* wkb = (f16*)w; w += (size_t)1024 * 1024 * 2;
  f16* wvb = (f16*)w; w += (size_t)1024 * 1024 * 2;
  f16* wob = (f16*)w; w += (size_t)1024 * 1024 * 2;
  f16* Qb  = (f16*)w; w += (size_t)2048 * 1024 * 2;
  f16* Kb  = (f16*)w; w += (size_t)2048 * 1024 * 2;
  f16* VTb = (f16*)w; w += (size_t)2048 * 1024 * 2;
  f16* AOb = (f16*)w; w += (size_t)2048 * 1024 * 2;
  float* btab = (float*)w; w += (size_t)16 * 4096 * 4;

  cast_all<<<6144, 256, 0, stream>>>(hs, wq, wk, wv, wo, hb, wqb, wkb, wvb, wob);
  build_bias<<<256, 256, 0, stream>>>(rb, btab);
  gemm_qkv<<<dim3(32, 8, 3), 256, 0, stream>>>(hb, wqb, wkb, wvb, Qb, Kb, VTb);
  attn_kernel<<<dim3(32, 16), 256, 0, stream>>>(Qb, Kb, VTb, btab, AOb);
  gemm_out<<<dim3(32, 8), 256, 0, stream>>>(AOb, wob, (float*)d_out);
}